// Round 5
// baseline (437.301 us; speedup 1.0000x reference)
//
#include <hip/hip_runtime.h>
#include <hip/hip_bf16.h>

typedef short shortx4 __attribute__((ext_vector_type(4)));
typedef short short8 __attribute__((ext_vector_type(8)));
typedef float floatx4 __attribute__((ext_vector_type(4)));

#define MFMA_BF16(A, B, C) __builtin_amdgcn_mfma_f32_16x16x32_bf16((A), (B), (C), 0, 0, 0)
#define LOG2E 1.44269504088896340736f

__device__ __forceinline__ float bf2f(const __hip_bfloat16 v) { return __bfloat162float(v); }

// branchless RNE fp32->bf16 (used only for weight preload; loop paths use
// the native v_cvt_pk_bf16_f32 via __float22bfloat162_rn / __float2bfloat16)
__device__ __forceinline__ unsigned rne_bits(float f) {
    unsigned u = __builtin_bit_cast(unsigned, f);
    return u + 0x7fffu + ((u >> 16) & 1u);
}
__device__ __forceinline__ unsigned pack_bf16(float a, float b) {
    return (rne_bits(b) & 0xffff0000u) | (rne_bits(a) >> 16);
}

// native packed cvt (single v_cvt_pk_bf16_f32, RNE — same rounding as above).
// union pun: __hip_bfloat162 is not trivially copyable -> no __builtin_bit_cast.
__device__ __forceinline__ unsigned cvt_pk(float a, float b) {
    union { __hip_bfloat162 p; unsigned u; } r;
    r.p = __float22bfloat162_rn(float2{a, b});
    return r.u;
}
__device__ __forceinline__ short cvt_s(float f) {
    union { __hip_bfloat16 p; short s; } r;
    r.p = __float2bfloat16(f);
    return r.s;
}

__device__ __forceinline__ short8 cvt8(const float4 a, const float4 b) {
    union { unsigned u[4]; short8 s; } r;
    r.u[0] = pack_bf16(a.x, a.y);
    r.u[1] = pack_bf16(a.z, a.w);
    r.u[2] = pack_bf16(b.x, b.y);
    r.u[3] = pack_bf16(b.z, b.w);
    return r.s;
}

// single ds_read_b128 MFMA frag (16B-aligned by construction: strides 136/72)
__device__ __forceinline__ short8 ld16(const short* p) {
    return *reinterpret_cast<const short8*>(__builtin_assume_aligned(p, 16));
}

__device__ __forceinline__ float fast_sigmoid(float x) {
    const float e = __builtin_amdgcn_exp2f(-x * LOG2E);
    return __builtin_amdgcn_rcpf(1.0f + e);
}
__device__ __forceinline__ float fast_tanh(float x) {
    const float e = __builtin_amdgcn_exp2f(x * (2.0f * LOG2E));
    return 1.0f - 2.0f * __builtin_amdgcn_rcpf(e + 1.0f);
}

// ---------------------------------------------------------------------------
// Kernel 1: GRU. Round-4b (r4 + compile fix): R3 structure (256 blocks = 1/CU;
// 192 blocks x one 16-row tile, 64 blocks x two tiles sharing weight B-frags)
// with the LDS instruction stream HALVED:
//  - h row stride 132 -> 136 shorts (272B, 16B-aligned), x 68 -> 72 (144B):
//    every A-frag is ONE ds_read_b128 (was 2x ds_read_b64 from 8B-aligned
//    rows). 6 read instrs/lane/tile-step instead of 12; derived bank map
//    (dword addr = 4c+16f+4q mod 32) is conflict-free per 8-lane phase.
//    Rationale: R0/R2/R3 all pace at ~3400cyc per 32-row step regardless of
//    TLP/ILP organization -> the lockstep per-step LDS convoy (all 8 waves
//    issue reads at once after the barrier) is the prime remaining suspect.
//  - native v_cvt_pk_bf16_f32 conversions in the loop (h write, x staging)
//    instead of 3-4-op hand RNE (identical rounding).
// Kept: plain __syncthreads (R1's fences regressed), 1-deep x prefetch,
// serial MFMA chains (NT=2 pacer already has 2-tile ILP).
// ---------------------------------------------------------------------------
template<int NT>
__device__ __forceinline__ void gru_body(
    const int r0,
    const float* __restrict__ obs,
    const float* __restrict__ W_ih,
    const float* __restrict__ W_hh,
    const float* __restrict__ b_ih,
    const float* __restrict__ b_hh,
    __hip_bfloat16* __restrict__ h_out,
    short* h_lds, short* x_lds)
{
    const int tid = threadIdx.x;
    const int w = tid >> 6;          // wave 0..7
    const int lane = tid & 63;
    const int q = lane >> 4;         // quad 0..3
    const int c = lane & 15;

    constexpr int HS = 136;               // h row stride (shorts), 272B = 16B*17
    constexpr int XS = 72;                // x row stride (shorts), 144B = 16B*9
    constexpr int HBUF = NT * 16 * HS;    // shorts per h buffer
    constexpr int XBUF = NT * 16 * XS;    // shorts per x buffer

    for (int i = tid; i < 2 * HBUF; i += 512) h_lds[i] = 0;

    // weight B-frags: B[k][n] = W[col][k], lane n=c, k=8q+j (+32 per frag).
    // SHARED across the NT row-tiles.
    short8 wih[3][2];
    short8 whh[3][4];
#pragma unroll
    for (int g = 0; g < 3; ++g) {
        const int col = g * 128 + w * 16 + c;
#pragma unroll
        for (int f = 0; f < 2; ++f) {
            const float4 a = *reinterpret_cast<const float4*>(W_ih + col * 64 + f * 32 + q * 8);
            const float4 b = *reinterpret_cast<const float4*>(W_ih + col * 64 + f * 32 + q * 8 + 4);
            wih[g][f] = cvt8(a, b);
        }
#pragma unroll
        for (int f = 0; f < 4; ++f) {
            const float4 a = *reinterpret_cast<const float4*>(W_hh + col * 128 + f * 32 + q * 8);
            const float4 b = *reinterpret_cast<const float4*>(W_hh + col * 128 + f * 32 + q * 8 + 4);
            whh[g][f] = cvt8(a, b);
        }
    }

    // bias as MFMA C operands (same col for all 4 acc rows)
    const int cc = w * 16 + c;
    const float br_ = b_ih[cc] + b_hh[cc];
    const float bz_ = b_ih[128 + cc] + b_hh[128 + cc];
    const float bin_ = b_ih[256 + cc];
    const float bhn_ = b_hh[256 + cc];
    const floatx4 cbias_r  = {br_, br_, br_, br_};
    const floatx4 cbias_z  = {bz_, bz_, bz_, bz_};
    const floatx4 cbias_in = {bin_, bin_, bin_, bin_};
    const floatx4 cbias_hn = {bhn_, bhn_, bhn_, bhn_};

    // x staging.
    // NT=1: 512 threads, (srow=tid>>5, scw=tid&31), float2 -> 1 dword.
    // NT=2: 512 threads, (srow=tid>>4, scw=tid&15), float4 -> uint2 (8B).
    int srow, scw;
    const float* xgs;
    float2 vn2;
    float4 vn4;
    if constexpr (NT == 1) {
        srow = tid >> 5; scw = tid & 31;
    } else {
        srow = tid >> 4; scw = tid & 15;
    }
    {
        const int rs = r0 + srow;
        const int bbs = rs / 5;
        const int jjs = rs - bbs * 5;
        if constexpr (NT == 1) {
            xgs = obs + bbs * 40960 + jjs * 64 + scw * 2;
            const float2 v0 = *reinterpret_cast<const float2*>(xgs);
            reinterpret_cast<unsigned*>(x_lds)[srow * 36 + scw] = cvt_pk(v0.x, v0.y);
            vn2 = *reinterpret_cast<const float2*>(xgs + 320);
        } else {
            xgs = obs + bbs * 40960 + jjs * 64 + scw * 4;
            const float4 v0 = *reinterpret_cast<const float4*>(xgs);
            *reinterpret_cast<uint2*>(&x_lds[srow * XS + scw * 4]) =
                uint2{cvt_pk(v0.x, v0.y), cvt_pk(v0.z, v0.w)};
            vn4 = *reinterpret_cast<const float4*>(xgs + 320);
        }
    }

    float hk[NT][4] = {};

    __syncthreads();  // h zeroed + x(t=0) staged

    int bufo = 0;       // h buffer offset (shorts), alternates 0 <-> HBUF
    for (int t = 0; t < 128; ++t) {
        const int nbufo = HBUF - bufo;
        const short* hb = &h_lds[bufo];
        const short* xb = &x_lds[(t & 1) * XBUF];

        // A-frags: single b128 each. lane row m=c within tile, k=8q+j (+32)
        short8 xc0[NT], xc1[NT], hf[NT][4];
#pragma unroll
        for (int T = 0; T < NT; ++T) {
            const short* xr = xb + (T * 16 + c) * XS;
            xc0[T] = ld16(xr + q * 8);
            xc1[T] = ld16(xr + 32 + q * 8);
            const short* hr = hb + (T * 16 + c) * HS;
#pragma unroll
            for (int f = 0; f < 4; ++f)
                hf[T][f] = ld16(hr + f * 32 + q * 8);
        }

        // stage x(t+1) from last iter's regs; prefetch x(t+2)
        const int tp = (t + 2) > 127 ? 127 : (t + 2);
        if constexpr (NT == 1) {
            unsigned* xw = reinterpret_cast<unsigned*>(&x_lds[((t + 1) & 1) * XBUF]);
            xw[srow * 36 + scw] = cvt_pk(vn2.x, vn2.y);
            vn2 = *reinterpret_cast<const float2*>(xgs + tp * 320);
        } else {
            *reinterpret_cast<uint2*>(&x_lds[((t + 1) & 1) * XBUF + srow * XS + scw * 4]) =
                uint2{cvt_pk(vn4.x, vn4.y), cvt_pk(vn4.z, vn4.w)};
            vn4 = *reinterpret_cast<const float4*>(xgs + tp * 320);
        }

        // gates: NT independent chains sharing weight frags
        floatx4 ar[NT], az[NT], an[NT], ah[NT];
#pragma unroll
        for (int T = 0; T < NT; ++T) {
            ar[T] = MFMA_BF16(xc0[T], wih[0][0], cbias_r);
            az[T] = MFMA_BF16(xc0[T], wih[1][0], cbias_z);
            an[T] = MFMA_BF16(xc0[T], wih[2][0], cbias_in);
        }
#pragma unroll
        for (int T = 0; T < NT; ++T) {
            ar[T] = MFMA_BF16(xc1[T], wih[0][1], ar[T]);
            az[T] = MFMA_BF16(xc1[T], wih[1][1], az[T]);
            an[T] = MFMA_BF16(xc1[T], wih[2][1], an[T]);
            ah[T] = MFMA_BF16(hf[T][0], whh[2][0], cbias_hn);
        }
#pragma unroll
        for (int f = 0; f < 4; ++f) {
#pragma unroll
            for (int T = 0; T < NT; ++T) {
                ar[T] = MFMA_BF16(hf[T][f], whh[0][f], ar[T]);
                az[T] = MFMA_BF16(hf[T][f], whh[1][f], az[T]);
                if (f > 0) ah[T] = MFMA_BF16(hf[T][f], whh[2][f], ah[T]);
            }
        }

        // GRU update; C/D layout: col=c, row=4q+i (within tile)
        short* hnb = &h_lds[nbufo];
#pragma unroll
        for (int T = 0; T < NT; ++T) {
#pragma unroll
            for (int i = 0; i < 4; ++i) {
                const float rr = fast_sigmoid(ar[T][i]);
                const float zz = fast_sigmoid(az[T][i]);
                const float nn = fast_tanh(an[T][i] + rr * ah[T][i]);
                const float hv = nn + zz * (hk[T][i] - nn);
                hk[T][i] = hv;
                hnb[(T * 16 + 4 * q + i) * HS + w * 16 + c] = cvt_s(hv);
            }
        }

        bufo = nbufo;
        __syncthreads();
    }

    // final hidden -> global ws (bf16): rows r0 + T*16 + 4q+i, col w*16+c
#pragma unroll
    for (int T = 0; T < NT; ++T)
#pragma unroll
        for (int i = 0; i < 4; ++i)
            h_out[(r0 + T * 16 + 4 * q + i) * 128 + w * 16 + c] = __float2bfloat16(hk[T][i]);
}

__global__ __launch_bounds__(512, 2) void gru_kernel(
    const float* __restrict__ obs,   // [1024,128,5,64] fp32
    const float* __restrict__ W_ih,  // [384,64]
    const float* __restrict__ W_hh,  // [384,128]
    const float* __restrict__ b_ih,  // [384]
    const float* __restrict__ b_hh,  // [384]
    __hip_bfloat16* __restrict__ h_out)  // [5120,128] bf16 (internal ws)
{
    __shared__ alignas(16) short h_lds[2 * 32 * 136];  // dual-tile size (17.4 KB)
    __shared__ alignas(16) short x_lds[2 * 32 * 72];   // dual-tile size (9.2 KB)

    const int bid = blockIdx.x;
    if (bid < 192)
        gru_body<1>(bid * 16, obs, W_ih, W_hh, b_ih, b_hh, h_out, h_lds, x_lds);
    else
        gru_body<2>(3072 + (bid - 192) * 32, obs, W_ih, W_hh, b_ih, b_hh, h_out,
                    h_lds, x_lds);
}

// ---------------------------------------------------------------------------
// Kernel 2: GAT + trunk MLP + actor/critic. ONE BLOCK PER BATCH (1024 blocks,
// 4 blocks/CU = 16 waves/CU). Matmuls K-split across threads + LDS reduce so
// all 256 threads work and load chains are short.
// ---------------------------------------------------------------------------
__global__ __launch_bounds__(256) void head_kernel(
    const __hip_bfloat16* __restrict__ h_in,  // [5120,128] bf16 ws
    const float* __restrict__ gat_W,    // [128,128]
    const float* __restrict__ att_src,  // [4,32]
    const float* __restrict__ att_dst,  // [4,32]
    const float* __restrict__ gat_b,    // [128]
    const float* __restrict__ W1,       // [128,128]
    const float* __restrict__ b1,       // [128]
    const float* __restrict__ W2,       // [128,64]
    const float* __restrict__ b2,       // [64]
    const float* __restrict__ actor_W,  // [5,64,4]
    const float* __restrict__ actor_b,  // [5,4]
    const float* __restrict__ critic_W, // [64]
    const float* __restrict__ critic_b, // [1]
    float* __restrict__ out)            // logits[1024*5*4] ++ value[1024], fp32
{
    __shared__ float hs[5][128];
    __shared__ float xp[5][128];
    __shared__ float gs[5][128];
    __shared__ float t1[5][128];
    __shared__ float t2[5][64];
    __shared__ float pp[1280];          // K-split partials (reused per stage)
    __shared__ float as_[5][4];
    __shared__ float ad_[5][4];

    const int tid = threadIdx.x;
    const int b = blockIdx.x;

    // load h (5 rows x 128)
    for (int i = tid; i < 640; i += 256)
        hs[i >> 7][i & 127] = bf2f(h_in[b * 640 + i]);
    __syncthreads();

    // ---- xp = h @ gat_W : thread (kh=tid>>7, col=tid&127), K-half of 64
    {
        const int kh = tid >> 7, col = tid & 127;
        float acc[5] = {0, 0, 0, 0, 0};
#pragma unroll 8
        for (int k2 = 0; k2 < 64; ++k2) {
            const int k = kh * 64 + k2;
            const float wv = gat_W[k * 128 + col];
#pragma unroll
            for (int i = 0; i < 5; ++i) acc[i] += hs[i][k] * wv;
        }
#pragma unroll
        for (int i = 0; i < 5; ++i) pp[kh * 640 + i * 128 + col] = acc[i];
    }
    __syncthreads();
    for (int i = tid; i < 640; i += 256)
        xp[i >> 7][i & 127] = pp[i] + pp[640 + i];
    __syncthreads();

    // per-node attention scores (5 rows x 4 heads x {src,dst} = 40)
    if (tid < 40) {
        const int row = tid >> 3;
        const int hd = (tid >> 1) & 3;
        const int which = tid & 1;
        const float* att = which ? att_dst : att_src;
        float acc = 0.0f;
#pragma unroll
        for (int d = 0; d < 32; ++d) acc += xp[row][hd * 32 + d] * att[hd * 32 + d];
        if (which) ad_[row][hd] = acc; else as_[row][hd] = acc;
    }
    __syncthreads();

    // softmax over chain neighbors {i-1,i,i+1} and aggregate
    for (int i = tid; i < 640; i += 256) {
        const int dst = i >> 7, col = i & 127, hd = col >> 5;
        const float adv = ad_[dst][hd];
        float ev[3]; int js[3]; int cnt = 0; float mx = -1e30f;
#pragma unroll
        for (int dj = -1; dj <= 1; ++dj) {
            const int j = dst + dj;
            if (j < 0 || j >= 5) continue;
            float e = as_[j][hd] + adv;
            e = e > 0.0f ? e : 0.2f * e;   // leaky_relu 0.2
            js[cnt] = j; ev[cnt] = e; mx = fmaxf(mx, e); ++cnt;
        }
        float s = 0.0f, num = 0.0f;
        for (int k = 0; k < cnt; ++k) {
            const float a = __builtin_amdgcn_exp2f((ev[k] - mx) * LOG2E);
            s += a; num += a * xp[js[k]][col];
        }
        gs[dst][col] = num * __builtin_amdgcn_rcpf(s) + gat_b[col];
    }
    __syncthreads();

    // ---- t1 = relu(g @ W1 + b1) : same K-split
    {
        const int kh = tid >> 7, col = tid & 127;
        float acc[5] = {0, 0, 0, 0, 0};
#pragma unroll 8
        for (int k2 = 0; k2 < 64; ++k2) {
            const int k = kh * 64 + k2;
            const float wv = W1[k * 128 + col];
#pragma unroll
            for (int i = 0; i < 5; ++i) acc[i] += gs[i][k] * wv;
        }
#pragma unroll
        for (int i = 0; i < 5; ++i) pp[kh * 640 + i * 128 + col] = acc[i];
    }
    __syncthreads();
    for (int i = tid; i < 640; i += 256)
        t1[i >> 7][i & 127] = fmaxf(pp[i] + pp[640 + i] + b1[i & 127], 0.0f);
    __syncthreads();

    // ---- t2 = relu(t1 @ W2 + b2) : thread (kq=tid>>6, col=tid&63), K-quarter 32
    {
        const int kq = tid >> 6, col = tid & 63;
        float acc[5] = {0, 0, 0, 0, 0};
#pragma unroll 8
        for (int k2 = 0; k2 < 32; ++k2) {
            const int k = kq * 32 + k2;
            const float wv = W2[k * 64 + col];
#pragma unroll
            for (int i = 0; i < 5; ++i) acc[i] += t1[i][k] * wv;
        }
#pragma unroll
        for (int i = 0; i < 5; ++i) pp[kq * 320 + i * 64 + col] = acc[i];
    }
    __syncthreads();
    for (int i = tid; i < 320; i += 256) {
        const int row = i >> 6, col = i & 63;
        t2[row][col] = fmaxf(pp[i] + pp[320 + i] + pp[640 + i] + pp[960 + i] + b2[col], 0.0f);
    }
    __syncthreads();

    // actor logits: 5 rows x 4 p
    if (tid < 20) {
        const int row = tid >> 2, p = tid & 3;
        float acc = actor_b[row * 4 + p];
#pragma unroll
        for (int o = 0; o < 64; ++o)
            acc += t2[row][o] * actor_W[row * 256 + o * 4 + p];
        out[(b * 5 + row) * 4 + p] = acc;
    }
    // critic on junction mean
    if (tid == 64) {
        float acc = 0.0f;
#pragma unroll
        for (int o = 0; o < 64; ++o) {
            float m = 0.0f;
#pragma unroll
            for (int j = 0; j < 5; ++j) m += t2[j][o];
            acc += (m * 0.2f) * critic_W[o];
        }
        out[20480 + b] = acc + critic_b[0];
    }
}

extern "C" void kernel_launch(void* const* d_in, const int* in_sizes, int n_in,
                              void* d_out, int out_size, void* d_ws, size_t ws_size,
                              hipStream_t stream) {
    (void)in_sizes; (void)n_in; (void)out_size; (void)ws_size;
    const float* obs      = (const float*)d_in[0];
    // d_in[1] = edge_index (fixed bidirectional 5-chain baked into kernel 2)
    const float* W_ih     = (const float*)d_in[2];
    const float* W_hh     = (const float*)d_in[3];
    const float* b_ih     = (const float*)d_in[4];
    const float* b_hh     = (const float*)d_in[5];
    const float* gat_W    = (const float*)d_in[6];
    const float* att_src  = (const float*)d_in[7];
    const float* att_dst  = (const float*)d_in[8];
    const float* gat_b    = (const float*)d_in[9];
    const float* W1       = (const float*)d_in[10];
    const float* b1       = (const float*)d_in[11];
    const float* W2       = (const float*)d_in[12];
    const float* b2       = (const float*)d_in[13];
    const float* actor_W  = (const float*)d_in[14];
    const float* actor_b  = (const float*)d_in[15];
    const float* critic_W = (const float*)d_in[16];
    const float* critic_b = (const float*)d_in[17];

    __hip_bfloat16* h_ws = (__hip_bfloat16*)d_ws;  // [5120,128] bf16 = 1.31 MB

    gru_kernel<<<256, 512, 0, stream>>>(obs, W_ih, W_hh, b_ih, b_hh, h_ws);
    head_kernel<<<1024, 256, 0, stream>>>(h_ws, gat_W, att_src, att_dst, gat_b,
                                          W1, b1, W2, b2, actor_W, actor_b,
                                          critic_W, critic_b,
                                          (float*)d_out);
}